// Round 1
// baseline (1393.020 us; speedup 1.0000x reference)
//
#include <hip/hip_runtime.h>

#define S_DIM 256
#define R_DIM 384
#define C_DIM 256
#define H_DIM 8
#define AC_DIM 32
#define HC_DIM 256
#define M_DIM (S_DIM * R_DIM)  // 98304 rows, m = r*S + s

typedef __attribute__((ext_vector_type(8))) short short8;
typedef __attribute__((ext_vector_type(4))) float floatx4;

__device__ __forceinline__ unsigned short f2bf(float f) {
  unsigned u = __float_as_uint(f);
  u += 0x7FFFu + ((u >> 16) & 1u);  // round-to-nearest-even
  return (unsigned short)(u >> 16);
}
__device__ __forceinline__ float bflo(unsigned u) { return __uint_as_float(u << 16); }
__device__ __forceinline__ float bfhi(unsigned u) { return __uint_as_float(u & 0xFFFF0000u); }
__device__ __forceinline__ unsigned packbf2(float a, float b) {
  return (unsigned)f2bf(a) | ((unsigned)f2bf(b) << 16);
}

// ---------------------------------------------------------------------------
// Kernel 1: per-row LayerNorm stats over C=256. Rows indexed in msa natural
// order p = s*R + r. One wave (64 lanes) per row, float4 loads.
// ---------------------------------------------------------------------------
__global__ __launch_bounds__(256) void ln_stats_kernel(
    const float* __restrict__ x, float* __restrict__ mu, float* __restrict__ rstd) {
  int row = blockIdx.x * 4 + (threadIdx.x >> 6);
  int lane = threadIdx.x & 63;
  const float4 v = ((const float4*)(x + (size_t)row * C_DIM))[lane];
  float s = v.x + v.y + v.z + v.w;
  float ss = v.x * v.x + v.y * v.y + v.z * v.z + v.w * v.w;
#pragma unroll
  for (int o = 32; o > 0; o >>= 1) {
    s += __shfl_down(s, o);
    ss += __shfl_down(ss, o);
  }
  if (lane == 0) {
    float m = s * (1.0f / C_DIM);
    float var = ss * (1.0f / C_DIM) - m * m;
    mu[row] = m;
    rstd[row] = rsqrtf(var + 1e-5f);
  }
}

// ---------------------------------------------------------------------------
// Kernel 2: fused LN + projection GEMM.
// A = LN(x) rows ordered m = r*S + s (reads msa row p = s*R + r), bf16.
// B = one of {wq,wk,wv,wg} selected by n-tile (n0 in [0,1024), 64-wide tiles
// never straddle a 256 boundary). MFMA 16x16x32 bf16, 64x64 tile, BK=32,
// 4 waves in 2x2 (m x n) arrangement, each wave 32x32 (2x2 mfma tiles).
// Epilogue: q *= 1/sqrt(32); g = sigmoid(. + bg). Stores bf16.
// ---------------------------------------------------------------------------
__global__ __launch_bounds__(256) void proj_kernel(
    const float* __restrict__ msa, const float* __restrict__ mu_arr,
    const float* __restrict__ rstd_arr, const float* __restrict__ ln_g,
    const float* __restrict__ ln_b, const float* __restrict__ wq,
    const float* __restrict__ wk, const float* __restrict__ wv,
    const float* __restrict__ wg, const float* __restrict__ bg,
    unsigned short* __restrict__ q_ws, unsigned short* __restrict__ k_ws,
    unsigned short* __restrict__ v_ws, unsigned short* __restrict__ g_ws) {
  __shared__ __align__(16) unsigned short As[64 * 32];  // [m][k]
  __shared__ __align__(16) unsigned short Bs[64 * 32];  // [n][k] (transposed)

  const int n0 = blockIdx.x * 64;
  const int m0 = blockIdx.y * 64;
  const int wi = n0 >> 8;       // 0:q 1:k 2:v 3:g
  const int ncol0 = n0 & 255;   // column base inside the selected W
  const float* wsel = (wi == 0) ? wq : (wi == 1) ? wk : (wi == 2) ? wv : wg;

  const int tid = threadIdx.x;
  const int wave = tid >> 6, lane = tid & 63;
  const int qd = lane >> 4, lm = lane & 15;
  const int wm = (wave & 1) * 32, wn = (wave >> 1) * 32;

  // A staging assignment: 4 threads per row, 8 elems each
  const int arow = tid >> 2;
  const int acol = (tid & 3) * 8;
  const int gm = m0 + arow;
  const int rr = gm >> 8;       // r   (S = 256)
  const int ss = gm & 255;      // s
  const int p = ss * R_DIM + rr;
  const float amu = mu_arr[p];
  const float ars = rstd_arr[p];
  const float* aptr = msa + (size_t)p * C_DIM;

  // B staging assignment: Bs[n][k] <- W[k0+bk][ncol0+bn .. +7]
  const int bk = tid >> 3;            // 0..31
  const int bn = (tid & 7) * 8;       // 0..56
  const float* bptr = wsel + ncol0 + bn;

  floatx4 acc[2][2];
#pragma unroll
  for (int i = 0; i < 2; ++i)
#pragma unroll
    for (int j = 0; j < 2; ++j) acc[i][j] = (floatx4){0.f, 0.f, 0.f, 0.f};

  for (int k0 = 0; k0 < C_DIM; k0 += 32) {
    // ---- stage A (LN on the fly) ----
    float4 x0 = *(const float4*)(aptr + k0 + acol);
    float4 x1 = *(const float4*)(aptr + k0 + acol + 4);
    float4 g0 = *(const float4*)(ln_g + k0 + acol);
    float4 g1 = *(const float4*)(ln_g + k0 + acol + 4);
    float4 b0 = *(const float4*)(ln_b + k0 + acol);
    float4 b1 = *(const float4*)(ln_b + k0 + acol + 4);
    unsigned short* ap = &As[arow * 32 + acol];
    ap[0] = f2bf((x0.x - amu) * ars * g0.x + b0.x);
    ap[1] = f2bf((x0.y - amu) * ars * g0.y + b0.y);
    ap[2] = f2bf((x0.z - amu) * ars * g0.z + b0.z);
    ap[3] = f2bf((x0.w - amu) * ars * g0.w + b0.w);
    ap[4] = f2bf((x1.x - amu) * ars * g1.x + b1.x);
    ap[5] = f2bf((x1.y - amu) * ars * g1.y + b1.y);
    ap[6] = f2bf((x1.z - amu) * ars * g1.z + b1.z);
    ap[7] = f2bf((x1.w - amu) * ars * g1.w + b1.w);
    // ---- stage B transposed ----
    const float* bp = bptr + (size_t)(k0 + bk) * HC_DIM;
    float4 w0 = *(const float4*)(bp);
    float4 w1 = *(const float4*)(bp + 4);
    Bs[(bn + 0) * 32 + bk] = f2bf(w0.x);
    Bs[(bn + 1) * 32 + bk] = f2bf(w0.y);
    Bs[(bn + 2) * 32 + bk] = f2bf(w0.z);
    Bs[(bn + 3) * 32 + bk] = f2bf(w0.w);
    Bs[(bn + 4) * 32 + bk] = f2bf(w1.x);
    Bs[(bn + 5) * 32 + bk] = f2bf(w1.y);
    Bs[(bn + 6) * 32 + bk] = f2bf(w1.z);
    Bs[(bn + 7) * 32 + bk] = f2bf(w1.w);
    __syncthreads();
    // ---- MFMA: A[m][k]: m=lane&15, k=quad*8+j ; B[n][k]: n=lane&15 ----
    short8 a0 = *(const short8*)&As[(wm + lm) * 32 + qd * 8];
    short8 a1 = *(const short8*)&As[(wm + 16 + lm) * 32 + qd * 8];
    short8 bv0 = *(const short8*)&Bs[(wn + lm) * 32 + qd * 8];
    short8 bv1 = *(const short8*)&Bs[(wn + 16 + lm) * 32 + qd * 8];
    acc[0][0] = __builtin_amdgcn_mfma_f32_16x16x32_bf16(a0, bv0, acc[0][0], 0, 0, 0);
    acc[0][1] = __builtin_amdgcn_mfma_f32_16x16x32_bf16(a0, bv1, acc[0][1], 0, 0, 0);
    acc[1][0] = __builtin_amdgcn_mfma_f32_16x16x32_bf16(a1, bv0, acc[1][0], 0, 0, 0);
    acc[1][1] = __builtin_amdgcn_mfma_f32_16x16x32_bf16(a1, bv1, acc[1][1], 0, 0, 0);
    __syncthreads();
  }

  // ---- epilogue: D col=lane&15, row=quad*4+reg ----
#pragma unroll
  for (int tm = 0; tm < 2; ++tm)
#pragma unroll
    for (int tn = 0; tn < 2; ++tn)
#pragma unroll
      for (int rg = 0; rg < 4; ++rg) {
        int m = m0 + wm + tm * 16 + qd * 4 + rg;
        int n = n0 + wn + tn * 16 + lm;
        float val = acc[tm][tn][rg];
        size_t off = (size_t)m * HC_DIM + (n & 255);
        if (wi == 0) {
          q_ws[off] = f2bf(val * 0.17677669529663689f);  // 1/sqrt(32)
        } else if (wi == 1) {
          k_ws[off] = f2bf(val);
        } else if (wi == 2) {
          v_ws[off] = f2bf(val);
        } else {
          float sg = 1.0f / (1.0f + __expf(-(val + bg[n & 255])));
          g_ws[off] = f2bf(sg);
        }
      }
}

// ---------------------------------------------------------------------------
// Kernel 3: attention per (r, h). Block = 256 threads = 256 queries.
// K staged fp32 in LDS (padded stride 36), V staged bf16 (stride 40),
// two-pass online softmax; gate applied; ctx written bf16.
// ---------------------------------------------------------------------------
__global__ __launch_bounds__(256) void attn_kernel(
    const unsigned short* __restrict__ q_ws, const unsigned short* __restrict__ k_ws,
    const unsigned short* __restrict__ v_ws, const unsigned short* __restrict__ g_ws,
    const float* __restrict__ mask, unsigned short* __restrict__ ctx_ws) {
  __shared__ __align__(16) float Ks[256 * 36];           // 36 KB
  __shared__ __align__(16) unsigned short Vs[256 * 40];  // 20 KB
  __shared__ float Bias[256];

  const int r = blockIdx.x;
  const int h = blockIdx.y;
  const int tid = threadIdx.x;
  const size_t rowbase = ((size_t)(r * S_DIM + tid)) * HC_DIM + h * AC_DIM;

  // stage K row tid (bf16 -> fp32) and V row tid (raw bf16)
  {
    const uint4* kp = (const uint4*)(k_ws + rowbase);
    float* krow = &Ks[tid * 36];
#pragma unroll
    for (int gi = 0; gi < 4; ++gi) {
      uint4 u = kp[gi];
      krow[gi * 8 + 0] = bflo(u.x); krow[gi * 8 + 1] = bfhi(u.x);
      krow[gi * 8 + 2] = bflo(u.y); krow[gi * 8 + 3] = bfhi(u.y);
      krow[gi * 8 + 4] = bflo(u.z); krow[gi * 8 + 5] = bfhi(u.z);
      krow[gi * 8 + 6] = bflo(u.w); krow[gi * 8 + 7] = bfhi(u.w);
    }
    const uint4* vp = (const uint4*)(v_ws + rowbase);
    uint4* vrow = (uint4*)&Vs[tid * 40];
#pragma unroll
    for (int gi = 0; gi < 4; ++gi) vrow[gi] = vp[gi];
    Bias[tid] = 1e9f * (mask[(size_t)tid * R_DIM + r] - 1.0f);
  }

  // q for this thread's query s = tid
  float q[32];
  {
    const uint4* qp = (const uint4*)(q_ws + rowbase);
#pragma unroll
    for (int gi = 0; gi < 4; ++gi) {
      uint4 u = qp[gi];
      q[gi * 8 + 0] = bflo(u.x); q[gi * 8 + 1] = bfhi(u.x);
      q[gi * 8 + 2] = bflo(u.y); q[gi * 8 + 3] = bfhi(u.y);
      q[gi * 8 + 4] = bflo(u.z); q[gi * 8 + 5] = bfhi(u.z);
      q[gi * 8 + 6] = bflo(u.w); q[gi * 8 + 7] = bfhi(u.w);
    }
  }
  __syncthreads();

  // pass 1: running max + denominator
  float mi = -1e30f, li = 0.0f;
  for (int t = 0; t < S_DIM; ++t) {
    const float* kr = &Ks[t * 36];
    float aff = Bias[t];
#pragma unroll
    for (int j = 0; j < 32; j += 4) {
      float4 kv = *(const float4*)(kr + j);
      aff += q[j] * kv.x + q[j + 1] * kv.y + q[j + 2] * kv.z + q[j + 3] * kv.w;
    }
    float nm = fmaxf(mi, aff);
    li = li * __expf(mi - nm) + __expf(aff - nm);
    mi = nm;
  }

  // pass 2: weights * V
  float acc[32];
#pragma unroll
  for (int j = 0; j < 32; ++j) acc[j] = 0.0f;
  for (int t = 0; t < S_DIM; ++t) {
    const float* kr = &Ks[t * 36];
    float aff = Bias[t];
#pragma unroll
    for (int j = 0; j < 32; j += 4) {
      float4 kv = *(const float4*)(kr + j);
      aff += q[j] * kv.x + q[j + 1] * kv.y + q[j + 2] * kv.z + q[j + 3] * kv.w;
    }
    float w = __expf(aff - mi);
    const uint4* vr = (const uint4*)&Vs[t * 40];
#pragma unroll
    for (int gi = 0; gi < 4; ++gi) {
      uint4 u = vr[gi];
      acc[gi * 8 + 0] += w * bflo(u.x); acc[gi * 8 + 1] += w * bfhi(u.x);
      acc[gi * 8 + 2] += w * bflo(u.y); acc[gi * 8 + 3] += w * bfhi(u.y);
      acc[gi * 8 + 4] += w * bflo(u.z); acc[gi * 8 + 5] += w * bfhi(u.z);
      acc[gi * 8 + 6] += w * bflo(u.w); acc[gi * 8 + 7] += w * bfhi(u.w);
    }
  }

  // gate + store bf16
  const float inv = 1.0f / li;
  const uint4* gp = (const uint4*)(g_ws + rowbase);
  uint4* cp = (uint4*)(ctx_ws + rowbase);
#pragma unroll
  for (int gi = 0; gi < 4; ++gi) {
    uint4 u = gp[gi];
    float o0 = acc[gi * 8 + 0] * inv * bflo(u.x);
    float o1 = acc[gi * 8 + 1] * inv * bfhi(u.x);
    float o2 = acc[gi * 8 + 2] * inv * bflo(u.y);
    float o3 = acc[gi * 8 + 3] * inv * bfhi(u.y);
    float o4 = acc[gi * 8 + 4] * inv * bflo(u.z);
    float o5 = acc[gi * 8 + 5] * inv * bfhi(u.z);
    float o6 = acc[gi * 8 + 6] * inv * bflo(u.w);
    float o7 = acc[gi * 8 + 7] * inv * bfhi(u.w);
    uint4 o;
    o.x = packbf2(o0, o1); o.y = packbf2(o2, o3);
    o.z = packbf2(o4, o5); o.w = packbf2(o6, o7);
    cp[gi] = o;
  }
}

// ---------------------------------------------------------------------------
// Kernel 4: out = ctx @ wo + bo, written transposed to [S, R, C].
// Same MFMA structure as proj.
// ---------------------------------------------------------------------------
__global__ __launch_bounds__(256) void out_kernel(
    const unsigned short* __restrict__ ctx, const float* __restrict__ wo,
    const float* __restrict__ bo, float* __restrict__ out) {
  __shared__ __align__(16) unsigned short As[64 * 32];
  __shared__ __align__(16) unsigned short Bs[64 * 32];

  const int n0 = blockIdx.x * 64;  // 0..255
  const int m0 = blockIdx.y * 64;
  const int tid = threadIdx.x;
  const int wave = tid >> 6, lane = tid & 63;
  const int qd = lane >> 4, lm = lane & 15;
  const int wm = (wave & 1) * 32, wn = (wave >> 1) * 32;

  const int arow = tid >> 2;
  const int acol = (tid & 3) * 8;
  const unsigned short* aptr = ctx + (size_t)(m0 + arow) * HC_DIM;
  const int bk = tid >> 3;
  const int bn = (tid & 7) * 8;

  floatx4 acc[2][2];
#pragma unroll
  for (int i = 0; i < 2; ++i)
#pragma unroll
    for (int j = 0; j < 2; ++j) acc[i][j] = (floatx4){0.f, 0.f, 0.f, 0.f};

  for (int k0 = 0; k0 < HC_DIM; k0 += 32) {
    *(uint4*)&As[arow * 32 + acol] = *(const uint4*)(aptr + k0 + acol);
    const float* bp = wo + (size_t)(k0 + bk) * C_DIM + n0 + bn;
    float4 w0 = *(const float4*)(bp);
    float4 w1 = *(const float4*)(bp + 4);
    Bs[(bn + 0) * 32 + bk] = f2bf(w0.x);
    Bs[(bn + 1) * 32 + bk] = f2bf(w0.y);
    Bs[(bn + 2) * 32 + bk] = f2bf(w0.z);
    Bs[(bn + 3) * 32 + bk] = f2bf(w0.w);
    Bs[(bn + 4) * 32 + bk] = f2bf(w1.x);
    Bs[(bn + 5) * 32 + bk] = f2bf(w1.y);
    Bs[(bn + 6) * 32 + bk] = f2bf(w1.z);
    Bs[(bn + 7) * 32 + bk] = f2bf(w1.w);
    __syncthreads();
    short8 a0 = *(const short8*)&As[(wm + lm) * 32 + qd * 8];
    short8 a1 = *(const short8*)&As[(wm + 16 + lm) * 32 + qd * 8];
    short8 bv0 = *(const short8*)&Bs[(wn + lm) * 32 + qd * 8];
    short8 bv1 = *(const short8*)&Bs[(wn + 16 + lm) * 32 + qd * 8];
    acc[0][0] = __builtin_amdgcn_mfma_f32_16x16x32_bf16(a0, bv0, acc[0][0], 0, 0, 0);
    acc[0][1] = __builtin_amdgcn_mfma_f32_16x16x32_bf16(a0, bv1, acc[0][1], 0, 0, 0);
    acc[1][0] = __builtin_amdgcn_mfma_f32_16x16x32_bf16(a1, bv0, acc[1][0], 0, 0, 0);
    acc[1][1] = __builtin_amdgcn_mfma_f32_16x16x32_bf16(a1, bv1, acc[1][1], 0, 0, 0);
    __syncthreads();
  }

#pragma unroll
  for (int tm = 0; tm < 2; ++tm)
#pragma unroll
    for (int tn = 0; tn < 2; ++tn)
#pragma unroll
      for (int rg = 0; rg < 4; ++rg) {
        int m = m0 + wm + tm * 16 + qd * 4 + rg;
        int n = n0 + wn + tn * 16 + lm;
        int rr = m >> 8;    // r
        int ss = m & 255;   // s
        out[((size_t)ss * R_DIM + rr) * C_DIM + n] = acc[tm][tn][rg] + bo[n];
      }
}

// ---------------------------------------------------------------------------
extern "C" void kernel_launch(void* const* d_in, const int* in_sizes, int n_in,
                              void* d_out, int out_size, void* d_ws, size_t ws_size,
                              hipStream_t stream) {
  const float* msa = (const float*)d_in[0];
  const float* mask = (const float*)d_in[1];
  const float* ln_g = (const float*)d_in[2];
  const float* ln_b = (const float*)d_in[3];
  const float* wq = (const float*)d_in[4];
  const float* wk = (const float*)d_in[5];
  const float* wv = (const float*)d_in[6];
  const float* wg = (const float*)d_in[7];
  const float* bg = (const float*)d_in[8];
  const float* wo = (const float*)d_in[9];
  const float* bo = (const float*)d_in[10];
  float* out = (float*)d_out;

  // workspace carve: 2 fp32 stat arrays + 5 bf16 [M,256] arrays ~= 252 MB
  char* w = (char*)d_ws;
  float* mu = (float*)w;            w += (size_t)M_DIM * 4;
  float* rstd = (float*)w;          w += (size_t)M_DIM * 4;
  unsigned short* q_ws = (unsigned short*)w;  w += (size_t)M_DIM * HC_DIM * 2;
  unsigned short* k_ws = (unsigned short*)w;  w += (size_t)M_DIM * HC_DIM * 2;
  unsigned short* v_ws = (unsigned short*)w;  w += (size_t)M_DIM * HC_DIM * 2;
  unsigned short* g_ws = (unsigned short*)w;  w += (size_t)M_DIM * HC_DIM * 2;
  unsigned short* ctx_ws = (unsigned short*)w;

  hipLaunchKernelGGL(ln_stats_kernel, dim3(M_DIM / 4), dim3(256), 0, stream,
                     msa, mu, rstd);
  hipLaunchKernelGGL(proj_kernel, dim3(16, M_DIM / 64), dim3(256), 0, stream,
                     msa, mu, rstd, ln_g, ln_b, wq, wk, wv, wg, bg,
                     q_ws, k_ws, v_ws, g_ws);
  hipLaunchKernelGGL(attn_kernel, dim3(R_DIM, H_DIM), dim3(256), 0, stream,
                     q_ws, k_ws, v_ws, g_ws, mask, ctx_ws);
  hipLaunchKernelGGL(out_kernel, dim3(C_DIM / 64, M_DIM / 64), dim3(256), 0, stream,
                     ctx_ws, wo, bo, out);
}

// Round 2
// 743.323 us; speedup vs baseline: 1.8740x; 1.8740x over previous
//
#include <hip/hip_runtime.h>

#define S_DIM 256
#define R_DIM 384
#define C_DIM 256
#define H_DIM 8
#define AC_DIM 32
#define HC_DIM 256
#define M_DIM (S_DIM * R_DIM)  // 98304 rows, m = r*S + s

typedef __attribute__((ext_vector_type(8))) short short8;
typedef __attribute__((ext_vector_type(4))) float floatx4;

__device__ __forceinline__ unsigned short f2bf(float f) {
  unsigned u = __float_as_uint(f);
  u += 0x7FFFu + ((u >> 16) & 1u);  // round-to-nearest-even
  return (unsigned short)(u >> 16);
}
__device__ __forceinline__ float bflo(unsigned u) { return __uint_as_float(u << 16); }
__device__ __forceinline__ float bfhi(unsigned u) { return __uint_as_float(u & 0xFFFF0000u); }
__device__ __forceinline__ float bf2f(unsigned short s) {
  return __uint_as_float(((unsigned)s) << 16);
}
__device__ __forceinline__ unsigned packbf2(float a, float b) {
  return (unsigned)f2bf(a) | ((unsigned)f2bf(b) << 16);
}

// ---------------------------------------------------------------------------
// Kernel 1: per-row LayerNorm stats over C=256. Rows indexed in msa natural
// order p = s*R + r. One wave (64 lanes) per row, float4 loads.
// ---------------------------------------------------------------------------
__global__ __launch_bounds__(256) void ln_stats_kernel(
    const float* __restrict__ x, float* __restrict__ mu, float* __restrict__ rstd) {
  int row = blockIdx.x * 4 + (threadIdx.x >> 6);
  int lane = threadIdx.x & 63;
  const float4 v = ((const float4*)(x + (size_t)row * C_DIM))[lane];
  float s = v.x + v.y + v.z + v.w;
  float ss = v.x * v.x + v.y * v.y + v.z * v.z + v.w * v.w;
#pragma unroll
  for (int o = 32; o > 0; o >>= 1) {
    s += __shfl_down(s, o);
    ss += __shfl_down(ss, o);
  }
  if (lane == 0) {
    float m = s * (1.0f / C_DIM);
    float var = ss * (1.0f / C_DIM) - m * m;
    mu[row] = m;
    rstd[row] = rsqrtf(var + 1e-5f);
  }
}

// ---------------------------------------------------------------------------
// Kernel 2: fused LN + projection GEMM (unchanged from round 1).
// ---------------------------------------------------------------------------
__global__ __launch_bounds__(256) void proj_kernel(
    const float* __restrict__ msa, const float* __restrict__ mu_arr,
    const float* __restrict__ rstd_arr, const float* __restrict__ ln_g,
    const float* __restrict__ ln_b, const float* __restrict__ wq,
    const float* __restrict__ wk, const float* __restrict__ wv,
    const float* __restrict__ wg, const float* __restrict__ bg,
    unsigned short* __restrict__ q_ws, unsigned short* __restrict__ k_ws,
    unsigned short* __restrict__ v_ws, unsigned short* __restrict__ g_ws) {
  __shared__ __align__(16) unsigned short As[64 * 32];  // [m][k]
  __shared__ __align__(16) unsigned short Bs[64 * 32];  // [n][k] (transposed)

  const int n0 = blockIdx.x * 64;
  const int m0 = blockIdx.y * 64;
  const int wi = n0 >> 8;       // 0:q 1:k 2:v 3:g
  const int ncol0 = n0 & 255;   // column base inside the selected W
  const float* wsel = (wi == 0) ? wq : (wi == 1) ? wk : (wi == 2) ? wv : wg;

  const int tid = threadIdx.x;
  const int wave = tid >> 6, lane = tid & 63;
  const int qd = lane >> 4, lm = lane & 15;
  const int wm = (wave & 1) * 32, wn = (wave >> 1) * 32;

  const int arow = tid >> 2;
  const int acol = (tid & 3) * 8;
  const int gm = m0 + arow;
  const int rr = gm >> 8;       // r   (S = 256)
  const int ss = gm & 255;      // s
  const int p = ss * R_DIM + rr;
  const float amu = mu_arr[p];
  const float ars = rstd_arr[p];
  const float* aptr = msa + (size_t)p * C_DIM;

  const int bk = tid >> 3;            // 0..31
  const int bn = (tid & 7) * 8;       // 0..56
  const float* bptr = wsel + ncol0 + bn;

  floatx4 acc[2][2];
#pragma unroll
  for (int i = 0; i < 2; ++i)
#pragma unroll
    for (int j = 0; j < 2; ++j) acc[i][j] = (floatx4){0.f, 0.f, 0.f, 0.f};

  for (int k0 = 0; k0 < C_DIM; k0 += 32) {
    float4 x0 = *(const float4*)(aptr + k0 + acol);
    float4 x1 = *(const float4*)(aptr + k0 + acol + 4);
    float4 g0 = *(const float4*)(ln_g + k0 + acol);
    float4 g1 = *(const float4*)(ln_g + k0 + acol + 4);
    float4 b0 = *(const float4*)(ln_b + k0 + acol);
    float4 b1 = *(const float4*)(ln_b + k0 + acol + 4);
    unsigned short* ap = &As[arow * 32 + acol];
    ap[0] = f2bf((x0.x - amu) * ars * g0.x + b0.x);
    ap[1] = f2bf((x0.y - amu) * ars * g0.y + b0.y);
    ap[2] = f2bf((x0.z - amu) * ars * g0.z + b0.z);
    ap[3] = f2bf((x0.w - amu) * ars * g0.w + b0.w);
    ap[4] = f2bf((x1.x - amu) * ars * g1.x + b1.x);
    ap[5] = f2bf((x1.y - amu) * ars * g1.y + b1.y);
    ap[6] = f2bf((x1.z - amu) * ars * g1.z + b1.z);
    ap[7] = f2bf((x1.w - amu) * ars * g1.w + b1.w);
    const float* bp = bptr + (size_t)(k0 + bk) * HC_DIM;
    float4 w0 = *(const float4*)(bp);
    float4 w1 = *(const float4*)(bp + 4);
    Bs[(bn + 0) * 32 + bk] = f2bf(w0.x);
    Bs[(bn + 1) * 32 + bk] = f2bf(w0.y);
    Bs[(bn + 2) * 32 + bk] = f2bf(w0.z);
    Bs[(bn + 3) * 32 + bk] = f2bf(w0.w);
    Bs[(bn + 4) * 32 + bk] = f2bf(w1.x);
    Bs[(bn + 5) * 32 + bk] = f2bf(w1.y);
    Bs[(bn + 6) * 32 + bk] = f2bf(w1.z);
    Bs[(bn + 7) * 32 + bk] = f2bf(w1.w);
    __syncthreads();
    short8 a0 = *(const short8*)&As[(wm + lm) * 32 + qd * 8];
    short8 a1 = *(const short8*)&As[(wm + 16 + lm) * 32 + qd * 8];
    short8 bv0 = *(const short8*)&Bs[(wn + lm) * 32 + qd * 8];
    short8 bv1 = *(const short8*)&Bs[(wn + 16 + lm) * 32 + qd * 8];
    acc[0][0] = __builtin_amdgcn_mfma_f32_16x16x32_bf16(a0, bv0, acc[0][0], 0, 0, 0);
    acc[0][1] = __builtin_amdgcn_mfma_f32_16x16x32_bf16(a0, bv1, acc[0][1], 0, 0, 0);
    acc[1][0] = __builtin_amdgcn_mfma_f32_16x16x32_bf16(a1, bv0, acc[1][0], 0, 0, 0);
    acc[1][1] = __builtin_amdgcn_mfma_f32_16x16x32_bf16(a1, bv1, acc[1][1], 0, 0, 0);
    __syncthreads();
  }

#pragma unroll
  for (int tm = 0; tm < 2; ++tm)
#pragma unroll
    for (int tn = 0; tn < 2; ++tn)
#pragma unroll
      for (int rg = 0; rg < 4; ++rg) {
        int m = m0 + wm + tm * 16 + qd * 4 + rg;
        int n = n0 + wn + tn * 16 + lm;
        float val = acc[tm][tn][rg];
        size_t off = (size_t)m * HC_DIM + (n & 255);
        if (wi == 0) {
          q_ws[off] = f2bf(val * 0.17677669529663689f);  // 1/sqrt(32)
        } else if (wi == 1) {
          k_ws[off] = f2bf(val);
        } else if (wi == 2) {
          v_ws[off] = f2bf(val);
        } else {
          float sg = 1.0f / (1.0f + __expf(-(val + bg[n & 255])));
          g_ws[off] = f2bf(sg);
        }
      }
}

// ---------------------------------------------------------------------------
// Kernel 3 (REWRITTEN): flash-style MFMA attention per (r, h).
// 4 waves x 64 queries. 32-key chunks, online softmax.
//  - Q A-frags + K B-frags loaded directly from global (contiguous 16B/lane).
//  - P round-trips LDS with column-interleaved layout (col' = lm*2+frag) so
//    writes are 4x ds_write_b32 and readback is 1x ds_read_b128.
//  - V staged in LDS transposed [dim][key'] with the SAME key permutation
//    baked in, so V B-frags are single ds_read_b128 per chunk.
// ---------------------------------------------------------------------------
#define PSTRIDE 40   // P_lds row stride (elements), multiple of 8, 2-way banks
#define VSTRIDE 264  // V_lds row stride (elements), multiple of 8

__global__ __launch_bounds__(256) void attn_kernel(
    const unsigned short* __restrict__ q_ws, const unsigned short* __restrict__ k_ws,
    const unsigned short* __restrict__ v_ws, const unsigned short* __restrict__ g_ws,
    const float* __restrict__ mask, unsigned short* __restrict__ ctx_ws) {
  __shared__ __align__(16) unsigned short V_lds[32 * VSTRIDE];   // 16.5 KB
  __shared__ __align__(16) unsigned short P_lds[4 * 16 * PSTRIDE];  // 5 KB
  __shared__ float Bias[S_DIM];                                  // 1 KB

  const int r = blockIdx.x;
  const int h = blockIdx.y;
  const int tid = threadIdx.x;
  const int wave = tid >> 6, lane = tid & 63;
  const int qd = lane >> 4, lm = lane & 15;
  const int qw = wave * 64;  // this wave's query base

  const size_t rS = (size_t)r * S_DIM;
  const int hb = h * AC_DIM;

  // ---- stage V transposed+permuted, and bias ----
  {
    const int s = tid;  // global key
    const unsigned short* vp = v_ws + (rS + s) * HC_DIM + hb;
    const int pos = (s & ~31) + ((s & 15) * 2) + ((s >> 4) & 1);
    uint4 u0 = *(const uint4*)(vp);
    uint4 u1 = *(const uint4*)(vp + 8);
    uint4 u2 = *(const uint4*)(vp + 16);
    uint4 u3 = *(const uint4*)(vp + 24);
    const unsigned w[16] = {u0.x, u0.y, u0.z, u0.w, u1.x, u1.y, u1.z, u1.w,
                            u2.x, u2.y, u2.z, u2.w, u3.x, u3.y, u3.z, u3.w};
#pragma unroll
    for (int d2 = 0; d2 < 16; ++d2) {
      V_lds[(d2 * 2 + 0) * VSTRIDE + pos] = (unsigned short)(w[d2] & 0xFFFF);
      V_lds[(d2 * 2 + 1) * VSTRIDE + pos] = (unsigned short)(w[d2] >> 16);
    }
    Bias[s] = 1e9f * (mask[(size_t)s * R_DIM + r] - 1.0f);
  }

  // ---- Q fragments (direct global, A-layout: m=lm, k=qd*8+j) ----
  short8 qf[4];
#pragma unroll
  for (int qi = 0; qi < 4; ++qi)
    qf[qi] = *(const short8*)(q_ws + (rS + qw + qi * 16 + lm) * HC_DIM + hb + qd * 8);

  float m_st[4][4], l_st[4][4];
  floatx4 oacc[4][2];
#pragma unroll
  for (int qi = 0; qi < 4; ++qi) {
#pragma unroll
    for (int rg = 0; rg < 4; ++rg) {
      m_st[qi][rg] = -1e30f;
      l_st[qi][rg] = 0.0f;
    }
    oacc[qi][0] = (floatx4){0.f, 0.f, 0.f, 0.f};
    oacc[qi][1] = (floatx4){0.f, 0.f, 0.f, 0.f};
  }

  __syncthreads();

  unsigned short* Pw = &P_lds[wave * 16 * PSTRIDE];
  const floatx4 zero4 = (floatx4){0.f, 0.f, 0.f, 0.f};

  for (int ch = 0; ch < 8; ++ch) {
    const int kb = ch * 32;
    const float b0 = Bias[kb + lm];
    const float b1 = Bias[kb + 16 + lm];
    // K B-frags direct from global: n=key=lm(+16), k=dim=qd*8+j
    short8 kf0 = *(const short8*)(k_ws + (rS + kb + lm) * HC_DIM + hb + qd * 8);
    short8 kf1 = *(const short8*)(k_ws + (rS + kb + 16 + lm) * HC_DIM + hb + qd * 8);
    // V B-frags from LDS: n=dim=lm(+16), k=local key qd*8+j (permuted order)
    short8 vf0 = *(const short8*)&V_lds[lm * VSTRIDE + kb + qd * 8];
    short8 vf1 = *(const short8*)&V_lds[(16 + lm) * VSTRIDE + kb + qd * 8];

#pragma unroll
    for (int qi = 0; qi < 4; ++qi) {
      floatx4 s0 = __builtin_amdgcn_mfma_f32_16x16x32_bf16(qf[qi], kf0, zero4, 0, 0, 0);
      floatx4 s1 = __builtin_amdgcn_mfma_f32_16x16x32_bf16(qf[qi], kf1, zero4, 0, 0, 0);
      unsigned pw[4];
#pragma unroll
      for (int rg = 0; rg < 4; ++rg) {
        float a0 = s0[rg] + b0;
        float a1 = s1[rg] + b1;
        // row max over the 32 keys of this chunk (16-lane butterfly)
        float t = fmaxf(a0, a1);
        t = fmaxf(t, __shfl_xor(t, 1));
        t = fmaxf(t, __shfl_xor(t, 2));
        t = fmaxf(t, __shfl_xor(t, 4));
        t = fmaxf(t, __shfl_xor(t, 8));
        float mold = m_st[qi][rg];
        float mnew = fmaxf(mold, t);
        float alpha = __expf(mold - mnew);
        float p0 = __expf(a0 - mnew);
        float p1 = __expf(a1 - mnew);
        float rs = p0 + p1;
        rs += __shfl_xor(rs, 1);
        rs += __shfl_xor(rs, 2);
        rs += __shfl_xor(rs, 4);
        rs += __shfl_xor(rs, 8);
        l_st[qi][rg] = l_st[qi][rg] * alpha + rs;
        m_st[qi][rg] = mnew;
        oacc[qi][0][rg] *= alpha;
        oacc[qi][1][rg] *= alpha;
        pw[rg] = packbf2(p0, p1);  // low=frag0(key lm), high=frag1(key 16+lm)
      }
      // P write: row = qd*4+rg, interleaved col' = lm*2+frag -> 1 b32 per rg
      unsigned* pbase = (unsigned*)Pw;
#pragma unroll
      for (int rg = 0; rg < 4; ++rg)
        pbase[((qd * 4 + rg) * PSTRIDE) / 2 + lm] = pw[rg];
      // P readback as A-frag: m=lm, k'=qd*8+j (contiguous b128)
      short8 pa = *(const short8*)&Pw[lm * PSTRIDE + qd * 8];
      oacc[qi][0] = __builtin_amdgcn_mfma_f32_16x16x32_bf16(pa, vf0, oacc[qi][0], 0, 0, 0);
      oacc[qi][1] = __builtin_amdgcn_mfma_f32_16x16x32_bf16(pa, vf1, oacc[qi][1], 0, 0, 0);
    }
  }

  // ---- epilogue: normalize, gate, store bf16 ----
#pragma unroll
  for (int qi = 0; qi < 4; ++qi) {
#pragma unroll
    for (int rg = 0; rg < 4; ++rg) {
      const float inv = 1.0f / l_st[qi][rg];
      const int row = qw + qi * 16 + qd * 4 + rg;
      const size_t base = (rS + row) * HC_DIM + hb;
      float o0 = oacc[qi][0][rg] * inv * bf2f(g_ws[base + lm]);
      float o1 = oacc[qi][1][rg] * inv * bf2f(g_ws[base + 16 + lm]);
      ctx_ws[base + lm] = f2bf(o0);
      ctx_ws[base + 16 + lm] = f2bf(o1);
    }
  }
}

// ---------------------------------------------------------------------------
// Kernel 4: out = ctx @ wo + bo, written transposed to [S, R, C]. Unchanged.
// ---------------------------------------------------------------------------
__global__ __launch_bounds__(256) void out_kernel(
    const unsigned short* __restrict__ ctx, const float* __restrict__ wo,
    const float* __restrict__ bo, float* __restrict__ out) {
  __shared__ __align__(16) unsigned short As[64 * 32];
  __shared__ __align__(16) unsigned short Bs[64 * 32];

  const int n0 = blockIdx.x * 64;  // 0..255
  const int m0 = blockIdx.y * 64;
  const int tid = threadIdx.x;
  const int wave = tid >> 6, lane = tid & 63;
  const int qd = lane >> 4, lm = lane & 15;
  const int wm = (wave & 1) * 32, wn = (wave >> 1) * 32;

  const int arow = tid >> 2;
  const int acol = (tid & 3) * 8;
  const unsigned short* aptr = ctx + (size_t)(m0 + arow) * HC_DIM;
  const int bk = tid >> 3;
  const int bn = (tid & 7) * 8;

  floatx4 acc[2][2];
#pragma unroll
  for (int i = 0; i < 2; ++i)
#pragma unroll
    for (int j = 0; j < 2; ++j) acc[i][j] = (floatx4){0.f, 0.f, 0.f, 0.f};

  for (int k0 = 0; k0 < HC_DIM; k0 += 32) {
    *(uint4*)&As[arow * 32 + acol] = *(const uint4*)(aptr + k0 + acol);
    const float* bp = wo + (size_t)(k0 + bk) * C_DIM + n0 + bn;
    float4 w0 = *(const float4*)(bp);
    float4 w1 = *(const float4*)(bp + 4);
    Bs[(bn + 0) * 32 + bk] = f2bf(w0.x);
    Bs[(bn + 1) * 32 + bk] = f2bf(w0.y);
    Bs[(bn + 2) * 32 + bk] = f2bf(w0.z);
    Bs[(bn + 3) * 32 + bk] = f2bf(w0.w);
    Bs[(bn + 4) * 32 + bk] = f2bf(w1.x);
    Bs[(bn + 5) * 32 + bk] = f2bf(w1.y);
    Bs[(bn + 6) * 32 + bk] = f2bf(w1.z);
    Bs[(bn + 7) * 32 + bk] = f2bf(w1.w);
    __syncthreads();
    short8 a0 = *(const short8*)&As[(wm + lm) * 32 + qd * 8];
    short8 a1 = *(const short8*)&As[(wm + 16 + lm) * 32 + qd * 8];
    short8 bv0 = *(const short8*)&Bs[(wn + lm) * 32 + qd * 8];
    short8 bv1 = *(const short8*)&Bs[(wn + 16 + lm) * 32 + qd * 8];
    acc[0][0] = __builtin_amdgcn_mfma_f32_16x16x32_bf16(a0, bv0, acc[0][0], 0, 0, 0);
    acc[0][1] = __builtin_amdgcn_mfma_f32_16x16x32_bf16(a0, bv1, acc[0][1], 0, 0, 0);
    acc[1][0] = __builtin_amdgcn_mfma_f32_16x16x32_bf16(a1, bv0, acc[1][0], 0, 0, 0);
    acc[1][1] = __builtin_amdgcn_mfma_f32_16x16x32_bf16(a1, bv1, acc[1][1], 0, 0, 0);
    __syncthreads();
  }

#pragma unroll
  for (int tm = 0; tm < 2; ++tm)
#pragma unroll
    for (int tn = 0; tn < 2; ++tn)
#pragma unroll
      for (int rg = 0; rg < 4; ++rg) {
        int m = m0 + wm + tm * 16 + qd * 4 + rg;
        int n = n0 + wn + tn * 16 + lm;
        int rr = m >> 8;    // r
        int ss = m & 255;   // s
        out[((size_t)ss * R_DIM + rr) * C_DIM + n] = acc[tm][tn][rg] + bo[n];
      }
}

// ---------------------------------------------------------------------------
extern "C" void kernel_launch(void* const* d_in, const int* in_sizes, int n_in,
                              void* d_out, int out_size, void* d_ws, size_t ws_size,
                              hipStream_t stream) {
  const float* msa = (const float*)d_in[0];
  const float* mask = (const float*)d_in[1];
  const float* ln_g = (const float*)d_in[2];
  const float* ln_b = (const float*)d_in[3];
  const float* wq = (const float*)d_in[4];
  const float* wk = (const float*)d_in[5];
  const float* wv = (const float*)d_in[6];
  const float* wg = (const float*)d_in[7];
  const float* bg = (const float*)d_in[8];
  const float* wo = (const float*)d_in[9];
  const float* bo = (const float*)d_in[10];
  float* out = (float*)d_out;

  char* w = (char*)d_ws;
  float* mu = (float*)w;            w += (size_t)M_DIM * 4;
  float* rstd = (float*)w;          w += (size_t)M_DIM * 4;
  unsigned short* q_ws = (unsigned short*)w;  w += (size_t)M_DIM * HC_DIM * 2;
  unsigned short* k_ws = (unsigned short*)w;  w += (size_t)M_DIM * HC_DIM * 2;
  unsigned short* v_ws = (unsigned short*)w;  w += (size_t)M_DIM * HC_DIM * 2;
  unsigned short* g_ws = (unsigned short*)w;  w += (size_t)M_DIM * HC_DIM * 2;
  unsigned short* ctx_ws = (unsigned short*)w;

  hipLaunchKernelGGL(ln_stats_kernel, dim3(M_DIM / 4), dim3(256), 0, stream,
                     msa, mu, rstd);
  hipLaunchKernelGGL(proj_kernel, dim3(16, M_DIM / 64), dim3(256), 0, stream,
                     msa, mu, rstd, ln_g, ln_b, wq, wk, wv, wg, bg,
                     q_ws, k_ws, v_ws, g_ws);
  hipLaunchKernelGGL(attn_kernel, dim3(R_DIM, H_DIM), dim3(256), 0, stream,
                     q_ws, k_ws, v_ws, g_ws, mask, ctx_ws);
  hipLaunchKernelGGL(out_kernel, dim3(C_DIM / 64, M_DIM / 64), dim3(256), 0, stream,
                     ctx_ws, wo, bo, out);
}

// Round 4
// 648.699 us; speedup vs baseline: 2.1474x; 1.1459x over previous
//
#include <hip/hip_runtime.h>

#define S_DIM 256
#define R_DIM 384
#define C_DIM 256
#define H_DIM 8
#define AC_DIM 32
#define HC_DIM 256
#define M_DIM (S_DIM * R_DIM)  // 98304 rows, m = r*S + s

typedef __attribute__((ext_vector_type(8))) short short8;
typedef __attribute__((ext_vector_type(4))) float floatx4;

__device__ __forceinline__ unsigned short f2bf(float f) {
  unsigned u = __float_as_uint(f);
  u += 0x7FFFu + ((u >> 16) & 1u);  // round-to-nearest-even
  return (unsigned short)(u >> 16);
}
__device__ __forceinline__ float bf2f(unsigned short s) {
  return __uint_as_float(((unsigned)s) << 16);
}
__device__ __forceinline__ unsigned packbf2(float a, float b) {
  return (unsigned)f2bf(a) | ((unsigned)f2bf(b) << 16);
}

// async global->LDS, 16B per lane; LDS dest = wave-uniform base + lane*16
#define GLD_LDS16(gp, lp)                                                      \
  __builtin_amdgcn_global_load_lds(                                            \
      (const __attribute__((address_space(1))) unsigned int*)(gp),             \
      (__attribute__((address_space(3))) unsigned int*)(lp), 16, 0, 0)

// ---------------------------------------------------------------------------
// Kernel A: weight pre-pass. Wt[n][k] bf16, n in [0,1280):
//   n<1024: {wq,wk,wv,wg}[k][n&255]; n>=1024: wo[k][n&255].
// 64x64 LDS transpose tiles.
// ---------------------------------------------------------------------------
__global__ __launch_bounds__(256) void wcat_kernel(
    const float* __restrict__ wq, const float* __restrict__ wk,
    const float* __restrict__ wv, const float* __restrict__ wg,
    const float* __restrict__ wo, unsigned short* __restrict__ wt) {
  __shared__ float tile[64][65];
  const int n0 = blockIdx.x * 64;  // 0..1216
  const int k0 = blockIdx.y * 64;
  const int wi = n0 >> 8;
  const float* src = (wi == 0) ? wq : (wi == 1) ? wk : (wi == 2) ? wv
                   : (wi == 3) ? wg : wo;
  const int col0 = n0 & 255;
  const int tx = threadIdx.x & 63;
  const int ty = threadIdx.x >> 6;
#pragma unroll
  for (int i = 0; i < 16; ++i) {
    int kl = ty + i * 4;
    tile[kl][tx] = src[(size_t)(k0 + kl) * 256 + col0 + tx];
  }
  __syncthreads();
#pragma unroll
  for (int i = 0; i < 16; ++i) {
    int nl = ty + i * 4;
    wt[(size_t)(n0 + nl) * 256 + k0 + tx] = f2bf(tile[tx][nl]);
  }
}

// ---------------------------------------------------------------------------
// Kernel B: fused LayerNorm -> bf16 x_ln in m-order (m = r*S + s).
// One wave per msa row p = s*R + r. float4 read, ushort4 write.
// ---------------------------------------------------------------------------
__global__ __launch_bounds__(256) void ln_kernel(
    const float* __restrict__ msa, const float* __restrict__ ln_g,
    const float* __restrict__ ln_b, unsigned short* __restrict__ xln) {
  const int p = blockIdx.x * 4 + (threadIdx.x >> 6);
  const int lane = threadIdx.x & 63;
  const float4 v = ((const float4*)(msa + (size_t)p * C_DIM))[lane];
  float s = v.x + v.y + v.z + v.w;
  float ss = v.x * v.x + v.y * v.y + v.z * v.z + v.w * v.w;
#pragma unroll
  for (int o = 1; o < 64; o <<= 1) {
    s += __shfl_xor(s, o);
    ss += __shfl_xor(ss, o);
  }
  const float mu = s * (1.0f / C_DIM);
  const float rstd = rsqrtf(ss * (1.0f / C_DIM) - mu * mu + 1e-5f);
  const float4 g = ((const float4*)ln_g)[lane];
  const float4 b = ((const float4*)ln_b)[lane];
  const int sq = p / R_DIM;          // s
  const int r = p - sq * R_DIM;      // r
  const size_t m = (size_t)r * S_DIM + sq;
  ushort4 o;
  o.x = f2bf((v.x - mu) * rstd * g.x + b.x);
  o.y = f2bf((v.y - mu) * rstd * g.y + b.y);
  o.z = f2bf((v.z - mu) * rstd * g.z + b.z);
  o.w = f2bf((v.w - mu) * rstd * g.w + b.w);
  *(ushort4*)(xln + m * C_DIM + lane * 4) = o;
}

// ---------------------------------------------------------------------------
// Kernel C: projection GEMM, m97-style. C[m][n] = xln[m][k] * Wt[n][k].
// 128x128 tile, BK=32, frag-major LDS groups (16 rows x 64 lanes x 16B),
// global_load_lds width-16 staging, lane-sequential ds_read_b128 frags.
// Epilogue: n>>8 selects q(scale)/k/v/g(sigmoid+bg), bf16 stores.
// ---------------------------------------------------------------------------
__global__ __launch_bounds__(256) void proj_kernel(
    const unsigned short* __restrict__ xln, const unsigned short* __restrict__ wt,
    const float* __restrict__ bg, unsigned short* __restrict__ q_ws,
    unsigned short* __restrict__ k_ws, unsigned short* __restrict__ v_ws,
    unsigned short* __restrict__ g_ws) {
  __shared__ __align__(16) unsigned short As[8 * 512];  // 8 KB, 8 groups
  __shared__ __align__(16) unsigned short Bs[8 * 512];  // 8 KB

  const int n0 = blockIdx.x * 128;
  const int m0 = blockIdx.y * 128;
  const int tid = threadIdx.x;
  const int wave = tid >> 6, lane = tid & 63;
  const int qd = lane >> 4, lm = lane & 15;
  const int wm = (wave & 1) * 64, wn = (wave >> 1) * 64;

  const int ga0 = wave * 2, ga1 = wave * 2 + 1;
  const unsigned short* agp0 = xln + (size_t)(m0 + ga0 * 16 + lm) * 256 + qd * 8;
  const unsigned short* agp1 = xln + (size_t)(m0 + ga1 * 16 + lm) * 256 + qd * 8;
  const unsigned short* bgp0 = wt + (size_t)(n0 + ga0 * 16 + lm) * 256 + qd * 8;
  const unsigned short* bgp1 = wt + (size_t)(n0 + ga1 * 16 + lm) * 256 + qd * 8;
  unsigned short* lA0 = &As[ga0 * 512];
  unsigned short* lA1 = &As[ga1 * 512];
  unsigned short* lB0 = &Bs[ga0 * 512];
  unsigned short* lB1 = &Bs[ga1 * 512];

  floatx4 acc[4][4];
#pragma unroll
  for (int i = 0; i < 4; ++i)
#pragma unroll
    for (int j = 0; j < 4; ++j) acc[i][j] = (floatx4){0.f, 0.f, 0.f, 0.f};

  for (int k0 = 0; k0 < 256; k0 += 32) {
    GLD_LDS16(agp0 + k0, lA0);
    GLD_LDS16(agp1 + k0, lA1);
    GLD_LDS16(bgp0 + k0, lB0);
    GLD_LDS16(bgp1 + k0, lB1);
    __syncthreads();
    short8 af[4], bf[4];
#pragma unroll
    for (int t = 0; t < 4; ++t) {
      af[t] = *(const short8*)((const char*)As + (size_t)(wm / 16 + t) * 1024 + lane * 16);
      bf[t] = *(const short8*)((const char*)Bs + (size_t)(wn / 16 + t) * 1024 + lane * 16);
    }
#pragma unroll
    for (int tm = 0; tm < 4; ++tm)
#pragma unroll
      for (int tn = 0; tn < 4; ++tn)
        acc[tm][tn] =
            __builtin_amdgcn_mfma_f32_16x16x32_bf16(af[tm], bf[tn], acc[tm][tn], 0, 0, 0);
    __syncthreads();
  }

  const int wi = n0 >> 8;
  const int colbase = (n0 & 255) + wn;
#pragma unroll
  for (int tm = 0; tm < 4; ++tm)
#pragma unroll
    for (int tn = 0; tn < 4; ++tn)
#pragma unroll
      for (int rg = 0; rg < 4; ++rg) {
        const int m = m0 + wm + tm * 16 + qd * 4 + rg;
        const int col = colbase + tn * 16 + lm;
        const size_t off = (size_t)m * 256 + col;
        float val = acc[tm][tn][rg];
        if (wi == 0) {
          q_ws[off] = f2bf(val * 0.17677669529663689f);  // 1/sqrt(32)
        } else if (wi == 1) {
          k_ws[off] = f2bf(val);
        } else if (wi == 2) {
          v_ws[off] = f2bf(val);
        } else {
          g_ws[off] = f2bf(1.0f / (1.0f + __expf(-(val + bg[col]))));
        }
      }
}

// ---------------------------------------------------------------------------
// Kernel D: flash-style MFMA attention per (r, h) — unchanged from round 2.
// ---------------------------------------------------------------------------
#define PSTRIDE 40
#define VSTRIDE 264

__global__ __launch_bounds__(256) void attn_kernel(
    const unsigned short* __restrict__ q_ws, const unsigned short* __restrict__ k_ws,
    const unsigned short* __restrict__ v_ws, const unsigned short* __restrict__ g_ws,
    const float* __restrict__ mask, unsigned short* __restrict__ ctx_ws) {
  __shared__ __align__(16) unsigned short V_lds[32 * VSTRIDE];
  __shared__ __align__(16) unsigned short P_lds[4 * 16 * PSTRIDE];
  __shared__ float Bias[S_DIM];

  const int r = blockIdx.x;
  const int h = blockIdx.y;
  const int tid = threadIdx.x;
  const int wave = tid >> 6, lane = tid & 63;
  const int qd = lane >> 4, lm = lane & 15;
  const int qw = wave * 64;

  const size_t rS = (size_t)r * S_DIM;
  const int hb = h * AC_DIM;

  {
    const int s = tid;
    const unsigned short* vp = v_ws + (rS + s) * HC_DIM + hb;
    const int pos = (s & ~31) + ((s & 15) * 2) + ((s >> 4) & 1);
    uint4 u0 = *(const uint4*)(vp);
    uint4 u1 = *(const uint4*)(vp + 8);
    uint4 u2 = *(const uint4*)(vp + 16);
    uint4 u3 = *(const uint4*)(vp + 24);
    const unsigned w[16] = {u0.x, u0.y, u0.z, u0.w, u1.x, u1.y, u1.z, u1.w,
                            u2.x, u2.y, u2.z, u2.w, u3.x, u3.y, u3.z, u3.w};
#pragma unroll
    for (int d2 = 0; d2 < 16; ++d2) {
      V_lds[(d2 * 2 + 0) * VSTRIDE + pos] = (unsigned short)(w[d2] & 0xFFFF);
      V_lds[(d2 * 2 + 1) * VSTRIDE + pos] = (unsigned short)(w[d2] >> 16);
    }
    Bias[s] = 1e9f * (mask[(size_t)s * R_DIM + r] - 1.0f);
  }

  short8 qf[4];
#pragma unroll
  for (int qi = 0; qi < 4; ++qi)
    qf[qi] = *(const short8*)(q_ws + (rS + qw + qi * 16 + lm) * HC_DIM + hb + qd * 8);

  float m_st[4][4], l_st[4][4];
  floatx4 oacc[4][2];
#pragma unroll
  for (int qi = 0; qi < 4; ++qi) {
#pragma unroll
    for (int rg = 0; rg < 4; ++rg) {
      m_st[qi][rg] = -1e30f;
      l_st[qi][rg] = 0.0f;
    }
    oacc[qi][0] = (floatx4){0.f, 0.f, 0.f, 0.f};
    oacc[qi][1] = (floatx4){0.f, 0.f, 0.f, 0.f};
  }

  __syncthreads();

  unsigned short* Pw = &P_lds[wave * 16 * PSTRIDE];
  const floatx4 zero4 = (floatx4){0.f, 0.f, 0.f, 0.f};

  for (int ch = 0; ch < 8; ++ch) {
    const int kb = ch * 32;
    const float b0 = Bias[kb + lm];
    const float b1 = Bias[kb + 16 + lm];
    short8 kf0 = *(const short8*)(k_ws + (rS + kb + lm) * HC_DIM + hb + qd * 8);
    short8 kf1 = *(const short8*)(k_ws + (rS + kb + 16 + lm) * HC_DIM + hb + qd * 8);
    short8 vf0 = *(const short8*)&V_lds[lm * VSTRIDE + kb + qd * 8];
    short8 vf1 = *(const short8*)&V_lds[(16 + lm) * VSTRIDE + kb + qd * 8];

#pragma unroll
    for (int qi = 0; qi < 4; ++qi) {
      floatx4 s0 = __builtin_amdgcn_mfma_f32_16x16x32_bf16(qf[qi], kf0, zero4, 0, 0, 0);
      floatx4 s1 = __builtin_amdgcn_mfma_f32_16x16x32_bf16(qf[qi], kf1, zero4, 0, 0, 0);
      unsigned pw[4];
#pragma unroll
      for (int rg = 0; rg < 4; ++rg) {
        float a0 = s0[rg] + b0;
        float a1 = s1[rg] + b1;
        float t = fmaxf(a0, a1);
        t = fmaxf(t, __shfl_xor(t, 1));
        t = fmaxf(t, __shfl_xor(t, 2));
        t = fmaxf(t, __shfl_xor(t, 4));
        t = fmaxf(t, __shfl_xor(t, 8));
        float mold = m_st[qi][rg];
        float mnew = fmaxf(mold, t);
        float alpha = __expf(mold - mnew);
        float p0 = __expf(a0 - mnew);
        float p1 = __expf(a1 - mnew);
        float rs = p0 + p1;
        rs += __shfl_xor(rs, 1);
        rs += __shfl_xor(rs, 2);
        rs += __shfl_xor(rs, 4);
        rs += __shfl_xor(rs, 8);
        l_st[qi][rg] = l_st[qi][rg] * alpha + rs;
        m_st[qi][rg] = mnew;
        oacc[qi][0][rg] *= alpha;
        oacc[qi][1][rg] *= alpha;
        pw[rg] = packbf2(p0, p1);
      }
      unsigned* pbase = (unsigned*)Pw;
#pragma unroll
      for (int rg = 0; rg < 4; ++rg)
        pbase[((qd * 4 + rg) * PSTRIDE) / 2 + lm] = pw[rg];
      short8 pa = *(const short8*)&Pw[lm * PSTRIDE + qd * 8];
      oacc[qi][0] = __builtin_amdgcn_mfma_f32_16x16x32_bf16(pa, vf0, oacc[qi][0], 0, 0, 0);
      oacc[qi][1] = __builtin_amdgcn_mfma_f32_16x16x32_bf16(pa, vf1, oacc[qi][1], 0, 0, 0);
    }
  }

#pragma unroll
  for (int qi = 0; qi < 4; ++qi) {
#pragma unroll
    for (int rg = 0; rg < 4; ++rg) {
      const float inv = 1.0f / l_st[qi][rg];
      const int row = qw + qi * 16 + qd * 4 + rg;
      const size_t base = (rS + row) * HC_DIM + hb;
      float o0 = oacc[qi][0][rg] * inv * bf2f(g_ws[base + lm]);
      float o1 = oacc[qi][1][rg] * inv * bf2f(g_ws[base + 16 + lm]);
      ctx_ws[base + lm] = f2bf(o0);
      ctx_ws[base + 16 + lm] = f2bf(o1);
    }
  }
}

// ---------------------------------------------------------------------------
// Kernel E: out = ctx @ wo + bo -> fp32 [S,R,C]. Same structure as proj.
// B = Wt rows [1024,1280).
// ---------------------------------------------------------------------------
__global__ __launch_bounds__(256) void out_kernel(
    const unsigned short* __restrict__ ctx, const unsigned short* __restrict__ wot,
    const float* __restrict__ bo, float* __restrict__ out) {
  __shared__ __align__(16) unsigned short As[8 * 512];
  __shared__ __align__(16) unsigned short Bs[8 * 512];

  const int n0 = blockIdx.x * 128;  // 0 or 128
  const int m0 = blockIdx.y * 128;
  const int tid = threadIdx.x;
  const int wave = tid >> 6, lane = tid & 63;
  const int qd = lane >> 4, lm = lane & 15;
  const int wm = (wave & 1) * 64, wn = (wave >> 1) * 64;

  const int ga0 = wave * 2, ga1 = wave * 2 + 1;
  const unsigned short* agp0 = ctx + (size_t)(m0 + ga0 * 16 + lm) * 256 + qd * 8;
  const unsigned short* agp1 = ctx + (size_t)(m0 + ga1 * 16 + lm) * 256 + qd * 8;
  const unsigned short* bgp0 = wot + (size_t)(n0 + ga0 * 16 + lm) * 256 + qd * 8;
  const unsigned short* bgp1 = wot + (size_t)(n0 + ga1 * 16 + lm) * 256 + qd * 8;
  unsigned short* lA0 = &As[ga0 * 512];
  unsigned short* lA1 = &As[ga1 * 512];
  unsigned short* lB0 = &Bs[ga0 * 512];
  unsigned short* lB1 = &Bs[ga1 * 512];

  floatx4 acc[4][4];
#pragma unroll
  for (int i = 0; i < 4; ++i)
#pragma unroll
    for (int j = 0; j < 4; ++j) acc[i][j] = (floatx4){0.f, 0.f, 0.f, 0.f};

  for (int k0 = 0; k0 < 256; k0 += 32) {
    GLD_LDS16(agp0 + k0, lA0);
    GLD_LDS16(agp1 + k0, lA1);
    GLD_LDS16(bgp0 + k0, lB0);
    GLD_LDS16(bgp1 + k0, lB1);
    __syncthreads();
    short8 af[4], bf[4];
#pragma unroll
    for (int t = 0; t < 4; ++t) {
      af[t] = *(const short8*)((const char*)As + (size_t)(wm / 16 + t) * 1024 + lane * 16);
      bf[t] = *(const short8*)((const char*)Bs + (size_t)(wn / 16 + t) * 1024 + lane * 16);
    }
#pragma unroll
    for (int tm = 0; tm < 4; ++tm)
#pragma unroll
      for (int tn = 0; tn < 4; ++tn)
        acc[tm][tn] =
            __builtin_amdgcn_mfma_f32_16x16x32_bf16(af[tm], bf[tn], acc[tm][tn], 0, 0, 0);
    __syncthreads();
  }

#pragma unroll
  for (int tm = 0; tm < 4; ++tm)
#pragma unroll
    for (int tn = 0; tn < 4; ++tn)
#pragma unroll
      for (int rg = 0; rg < 4; ++rg) {
        const int m = m0 + wm + tm * 16 + qd * 4 + rg;
        const int n = n0 + wn + tn * 16 + lm;
        const int rr = m >> 8;   // r
        const int sc = m & 255;  // s
        out[((size_t)sc * R_DIM + rr) * C_DIM + n] = acc[tm][tn][rg] + bo[n];
      }
}

// ---------------------------------------------------------------------------
extern "C" void kernel_launch(void* const* d_in, const int* in_sizes, int n_in,
                              void* d_out, int out_size, void* d_ws, size_t ws_size,
                              hipStream_t stream) {
  const float* msa = (const float*)d_in[0];
  const float* mask = (const float*)d_in[1];
  const float* ln_g = (const float*)d_in[2];
  const float* ln_b = (const float*)d_in[3];
  const float* wq = (const float*)d_in[4];
  const float* wk = (const float*)d_in[5];
  const float* wv = (const float*)d_in[6];
  const float* wg = (const float*)d_in[7];
  const float* bg = (const float*)d_in[8];
  const float* wo = (const float*)d_in[9];
  const float* bo = (const float*)d_in[10];
  float* out = (float*)d_out;

  // workspace carve (~252.3 MB): Wt | x_ln (aliased as ctx) | q | k | v | g
  unsigned short* wt = (unsigned short*)d_ws;
  unsigned short* xln = wt + (size_t)1280 * 256;
  unsigned short* q_ws = xln + (size_t)M_DIM * 256;
  unsigned short* k_ws = q_ws + (size_t)M_DIM * 256;
  unsigned short* v_ws = k_ws + (size_t)M_DIM * 256;
  unsigned short* g_ws = v_ws + (size_t)M_DIM * 256;
  unsigned short* ctx_ws = xln;  // alias: x_ln dead after proj
  unsigned short* wot = wt + (size_t)1024 * 256;

  hipLaunchKernelGGL(wcat_kernel, dim3(20, 4), dim3(256), 0, stream,
                     wq, wk, wv, wg, wo, wt);
  hipLaunchKernelGGL(ln_kernel, dim3(M_DIM / 4), dim3(256), 0, stream,
                     msa, ln_g, ln_b, xln);
  hipLaunchKernelGGL(proj_kernel, dim3(8, M_DIM / 128), dim3(256), 0, stream,
                     xln, wt, bg, q_ws, k_ws, v_ws, g_ws);
  hipLaunchKernelGGL(attn_kernel, dim3(R_DIM, H_DIM), dim3(256), 0, stream,
                     q_ws, k_ws, v_ws, g_ws, mask, ctx_ws);
  hipLaunchKernelGGL(out_kernel, dim3(2, M_DIM / 128), dim3(256), 0, stream,
                     ctx_ws, wot, bo, out);
}